// Round 15
// baseline (215.790 us; speedup 1.0000x reference)
//
#include <hip/hip_runtime.h>
#include <stdint.h>

#define LEN 512
#define NB 64
#define NCX 64
#define NCV 4
#define NCU 4

typedef float f4 __attribute__((ext_vector_type(4)));
typedef float f4u __attribute__((ext_vector_type(4), aligned(4)));  // 4B-aligned

// ---------------- Threefry-2x32, 20 rounds, key = (0, 42) ----------------
__device__ __forceinline__ uint32_t rotl32(uint32_t v, int r) {
  return (v << r) | (v >> (32 - r));
}

__device__ __forceinline__ void threefry2x32_k042(uint32_t c0, uint32_t c1,
                                                  uint32_t& o0, uint32_t& o1) {
  const uint32_t ks0 = 0u, ks1 = 42u;
  const uint32_t ks2 = 0u ^ 42u ^ 0x1BD11BDAu;
  uint32_t x0 = c0 + ks0;
  uint32_t x1 = c1 + ks1;
#define TF_ROUND(R) { x0 += x1; x1 = rotl32(x1, R); x1 ^= x0; }
  TF_ROUND(13) TF_ROUND(15) TF_ROUND(26) TF_ROUND(6)
  x0 += ks1; x1 += ks2 + 1u;
  TF_ROUND(17) TF_ROUND(29) TF_ROUND(16) TF_ROUND(24)
  x0 += ks2; x1 += ks0 + 2u;
  TF_ROUND(13) TF_ROUND(15) TF_ROUND(26) TF_ROUND(6)
  x0 += ks0; x1 += ks1 + 3u;
  TF_ROUND(17) TF_ROUND(29) TF_ROUND(16) TF_ROUND(24)
  x0 += ks1; x1 += ks2 + 4u;
  TF_ROUND(13) TF_ROUND(15) TF_ROUND(26) TF_ROUND(6)
  x0 += ks2; x1 += ks0 + 5u;
#undef TF_ROUND
  o0 = x0; o1 = x1;
}

// ---------------- Single fused kernel ----------------
// Prefix-mask structure exploited: valid slots are [0, nv) (prefix), invalid
// are the contiguous tail [nv, 512). Permutation = random perm of the tail
// into positions [0, n_inv) + pure shift src[t] = t - n_inv for t >= n_inv.
// uu phase: shift columns (j >= n_inv, 75%) are copied DIRECTLY global->reg->
// global at offset j-n_inv (no LDS); head columns (j < n_inv) gather from an
// LDS-staged copy of the input row TAIL [nv_al, 512) (<= 1KB, 1 f4/lane).
__global__ __launch_bounds__(256) void fused_trim(
    const float* __restrict__ in, float* __restrict__ out,
    const float* __restrict__ xin, const float* __restrict__ vin,
    float* __restrict__ xout, float* __restrict__ vout,
    float* __restrict__ mask_out, const void* __restrict__ mask) {
  __shared__ alignas(16) uint32_t s_pack[LEN];
  __shared__ int s_src[LEN];
  __shared__ alignas(16) float s_tail[4][256];
  __shared__ int wsum[8];
  __shared__ int woff[9];

  const int tid = threadIdx.x;
  const int wave = tid >> 6, lane = tid & 63;
  const int blk = blockIdx.x;
  const int b = blk >> 6;                      // 64 blocks per batch sample
  const int k = blk & 63;

  // ================= perm phase (2 positions per thread) =================
  const int l0 = tid, l1 = tid + 256;
  const uint32_t w0 = ((const uint32_t*)mask)[0];
  bool valid0, valid1;
  if (w0 == 1u) {                              // int32 0/1
    valid0 = ((const int*)mask)[b * LEN + l0] != 0;
    valid1 = ((const int*)mask)[b * LEN + l1] != 0;
  } else if (w0 == 0x3F800000u) {              // float32 0.0/1.0
    valid0 = ((const float*)mask)[b * LEN + l0] != 0.0f;
    valid1 = ((const float*)mask)[b * LEN + l1] != 0.0f;
  } else {                                     // 1-byte bool
    valid0 = ((const unsigned char*)mask)[b * LEN + l0] != 0;
    valid1 = ((const unsigned char*)mask)[b * LEN + l1] != 0;
  }
  const bool inv0 = !valid0, inv1 = !valid1;

  uint32_t a, c, me0, me1;
  threefry2x32_k042(0u, (uint32_t)(b * LEN + l0), a, c);
  me0 = ((((a ^ c) >> 9) & 0x7FFFFFu) << 9) | (uint32_t)(511 - l0);
  threefry2x32_k042(0u, (uint32_t)(b * LEN + l1), a, c);
  me1 = ((((a ^ c) >> 9) & 0x7FFFFFu) << 9) | (uint32_t)(511 - l1);

  const unsigned long long bal0 = __ballot(inv0);
  const unsigned long long bal1 = __ballot(inv1);
  const unsigned long long lmask = (1ull << lane) - 1ull;
  const int lower0 = __popcll(bal0 & lmask);
  const int lower1 = __popcll(bal1 & lmask);
  if (lane == 0) {
    wsum[wave] = __popcll(bal0);
    wsum[4 + wave] = __popcll(bal1);
  }
  __syncthreads();
  if (tid == 0) {
    int acc = 0;
    for (int w = 0; w < 8; ++w) { woff[w] = acc; acc += wsum[w]; }
    woff[8] = acc;
  }
  __syncthreads();
  const int n_inv = woff[8];
  const int ib0 = woff[wave] + lower0;
  const int ib1 = woff[4 + wave] + lower1;
  if (inv0) s_pack[ib0] = me0;
  if (inv1) s_pack[ib1] = me1;
  __syncthreads();

  int r0 = 0, r1 = 0;
  if (inv0 || inv1) {
    int j = 0;
    for (; j + 8 <= n_inv; j += 8) {
      const uint4 p0 = *(const uint4*)&s_pack[j];
      const uint4 p1 = *(const uint4*)&s_pack[j + 4];
      r0 += (int)(p0.x > me0) + (int)(p0.y > me0) + (int)(p0.z > me0) +
            (int)(p0.w > me0) + (int)(p1.x > me0) + (int)(p1.y > me0) +
            (int)(p1.z > me0) + (int)(p1.w > me0);
      r1 += (int)(p0.x > me1) + (int)(p0.y > me1) + (int)(p0.z > me1) +
            (int)(p0.w > me1) + (int)(p1.x > me1) + (int)(p1.y > me1) +
            (int)(p1.z > me1) + (int)(p1.w > me1);
    }
    for (; j < n_inv; ++j) {
      const uint32_t kj = s_pack[j];
      r0 += (int)(kj > me0);
      r1 += (int)(kj > me1);
    }
  }
  const int pos0 = inv0 ? r0 : n_inv + (l0 - ib0);
  const int pos1 = inv1 ? r1 : n_inv + (l1 - ib1);
  s_src[pos0] = l0;
  s_src[pos1] = l1;

  const int nv = LEN - n_inv;
  const int ml = nv < 1 ? 1 : nv;
  if (k == 0) {
    mask_out[b * LEN + l0] = (l0 >= n_inv && l0 < ml) ? 1.0f : 0.0f;
    mask_out[b * LEN + l1] = (l1 >= n_inv && l1 < ml) ? 1.0f : 0.0f;
  }
  __syncthreads();                             // s_src complete

  // ================= uu streaming phase =================
  const int orow0 = blk * 32 + wave * 8;       // global OUTPUT row id
  const int i0 = orow0 & (LEN - 1);
  const long plane = (long)(orow0 & ~(LEN - 1)) * LEN;
  const int lane4 = lane * 4;
  const int nv_al = nv & ~3;                   // aligned tail start (>= 256)
  const int tail_len = LEN - nv_al;            // <= 256
  const bool stg = lane4 < tail_len;           // this lane stages tail f4

  int rs[8];
#pragma unroll
  for (int r = 0; r < 8; ++r) rs[r] = s_src[i0 + r];

  // head-column gather indices (only meaningful where lane4+kk < n_inv)
  int hc[4];
#pragma unroll
  for (int kk = 0; kk < 4; ++kk) {
    const int cj = lane4 + kk;
    hc[kk] = (cj < n_inv) ? (s_src[cj] - nv_al) : 0;
  }

  // upfront tail-stage loads for all 8 rows (1 f4/lane, 16B-aligned)
  f4 st[8];
#pragma unroll
  for (int r = 0; r < 8; ++r) {
    if (stg) st[r] = *(const f4*)(in + plane + (long)rs[r] * LEN + nv_al + lane4);
  }

  float* myt = &s_tail[wave][0];
  float* op0 = out + plane + (long)i0 * LEN + lane4;

#pragma unroll
  for (int r = 0; r < 8; ++r) {
    const float* ipr = in + plane + (long)rs[r] * LEN;
    // shift-column direct loads (offset j - n_inv; 4B-aligned f4)
    f4 sh1 = *(const f4u*)(ipr + 256 + lane4 - n_inv);  // seg1 always shift
    f4 sh0;
    if (lane4 >= n_inv) sh0 = *(const f4u*)(ipr + lane4 - n_inv);
    // stage this row's tail, then gather head columns (same-wave DS order)
    if (stg) *(f4*)(myt + lane4) = st[r];
    f4 q0;
    if (lane4 + 3 < n_inv) {                   // pure head gather
      q0.x = myt[hc[0]]; q0.y = myt[hc[1]]; q0.z = myt[hc[2]]; q0.w = myt[hc[3]];
    } else if (lane4 >= n_inv) {               // pure shift
      q0 = sh0;
    } else {                                   // boundary lane (<=1 per wave)
      q0.x = (lane4 + 0 < n_inv) ? myt[hc[0]] : ipr[lane4 + 0 - n_inv];
      q0.y = (lane4 + 1 < n_inv) ? myt[hc[1]] : ipr[lane4 + 1 - n_inv];
      q0.z = (lane4 + 2 < n_inv) ? myt[hc[2]] : ipr[lane4 + 2 - n_inv];
      q0.w = (lane4 + 3 < n_inv) ? myt[hc[3]] : ipr[lane4 + 3 - n_inv];
    }
    f4* op = (f4*)(op0 + (long)r * LEN);
    op[0] = q0;                                // dense 1KB store (seg0)
    *(f4*)((float*)op + 256) = sh1;            // dense 1KB store (seg1)
  }

  // ================= fused x/v gather + trim for this (b, k) =============
  {
    const float* xrow = xin + (long)((b << 6) + k) * LEN;
    float* orow = xout + (long)((b << 6) + k) * LEN;
    for (int p = tid; p < LEN; p += 256) {
      orow[p] = (p < ml) ? xrow[s_src[p]] : 0.0f;
    }
  }
  if (k < NCV) {
    const float* vrow = vin + (long)((b << 2) + k) * LEN;
    float* orow = vout + (long)((b << 2) + k) * LEN;
    for (int p = tid; p < LEN; p += 256) {
      orow[p] = (p < ml) ? vrow[s_src[p]] : 0.0f;
    }
  }
}

extern "C" void kernel_launch(void* const* d_in, const int* in_sizes, int n_in,
                              void* d_out, int out_size, void* d_ws, size_t ws_size,
                              hipStream_t stream) {
  const float* x  = (const float*)d_in[0];   // (64,64,512)
  const float* v  = (const float*)d_in[1];   // (64,4,512)
  const float* uu = (const float*)d_in[2];   // (64,4,512,512)
  const void*  mask = d_in[3];               // (64,1,512)

  float* out   = (float*)d_out;
  float* out_x = out;                        // 2,097,152
  float* out_v = out + 2097152;              // 131,072
  float* out_m = out + 2228224;              // 32,768
  float* out_u = out + 2260992;              // 67,108,864

  fused_trim<<<NB * NCU * LEN / 32, 256, 0, stream>>>(
      uu, out_u, x, v, out_x, out_v, out_m, mask);
}

// Round 16
// 112.189 us; speedup vs baseline: 1.9235x; 1.9235x over previous
//
#include <hip/hip_runtime.h>
#include <stdint.h>

#define LEN 512
#define NB 64
#define NCX 64
#define NCV 4
#define NCU 4

typedef float f4 __attribute__((ext_vector_type(4)));

// ---------------- Threefry-2x32, 20 rounds, key = (0, 42) ----------------
__device__ __forceinline__ uint32_t rotl32(uint32_t v, int r) {
  return (v << r) | (v >> (32 - r));
}

__device__ __forceinline__ void threefry2x32_k042(uint32_t c0, uint32_t c1,
                                                  uint32_t& o0, uint32_t& o1) {
  const uint32_t ks0 = 0u, ks1 = 42u;
  const uint32_t ks2 = 0u ^ 42u ^ 0x1BD11BDAu;
  uint32_t x0 = c0 + ks0;
  uint32_t x1 = c1 + ks1;
#define TF_ROUND(R) { x0 += x1; x1 = rotl32(x1, R); x1 ^= x0; }
  TF_ROUND(13) TF_ROUND(15) TF_ROUND(26) TF_ROUND(6)
  x0 += ks1; x1 += ks2 + 1u;
  TF_ROUND(17) TF_ROUND(29) TF_ROUND(16) TF_ROUND(24)
  x0 += ks2; x1 += ks0 + 2u;
  TF_ROUND(13) TF_ROUND(15) TF_ROUND(26) TF_ROUND(6)
  x0 += ks0; x1 += ks1 + 3u;
  TF_ROUND(17) TF_ROUND(29) TF_ROUND(16) TF_ROUND(24)
  x0 += ks1; x1 += ks2 + 4u;
  TF_ROUND(13) TF_ROUND(15) TF_ROUND(26) TF_ROUND(6)
  x0 += ks2; x1 += ks0 + 5u;
#undef TF_ROUND
  o0 = x0; o1 = x1;
}

// ---------------- Single fused kernel (direction A, loads-first) ----------
// out[b,c,i,j] = in[b,c,src[i],src[j]]  <=>  out[b,c,dst[i'],j] = in[b,c,i',src[j]].
// Block owns 32 consecutive INPUT rows: their 16 dense f4 loads depend only
// on blockIdx, so they issue BEFORE the perm phase; the ~1us perm VALU work
// runs while the row data streams in (HBM latency hidden). After barrier:
// wave-private LDS row stage -> column gather -> scatter row store (s_dst).
// All f4 accesses 16B-aligned (R15's misalignment lesson).
__global__ __launch_bounds__(256) void fused_trim(
    const float* __restrict__ in, float* __restrict__ out,
    const float* __restrict__ xin, const float* __restrict__ vin,
    float* __restrict__ xout, float* __restrict__ vout,
    float* __restrict__ mask_out, const void* __restrict__ mask) {
  __shared__ alignas(16) uint32_t s_pack[LEN];
  __shared__ int s_src[LEN];
  __shared__ int s_dst[LEN];
  __shared__ float s_row[4][LEN];
  __shared__ int wsum[8];
  __shared__ int woff[9];

  const int tid = threadIdx.x;
  const int wave = tid >> 6, lane = tid & 63;
  const int blk = blockIdx.x;
  const int b = blk >> 6;                      // 64 blocks per batch sample
  const int k = blk & 63;

  // ======== phase 0: issue all 16 input-row loads (perm-independent) =====
  const int irow0 = blk * 32 + wave * 8;       // global INPUT row id
  const int i0 = irow0 & (LEN - 1);
  const long plane = (long)(irow0 & ~(LEN - 1)) * LEN;
  const float* ip = in + plane + (long)i0 * LEN + lane * 4;

  f4 a0[8], a1[8];
#pragma unroll
  for (int r = 0; r < 8; ++r) {
    a0[r] = *(const f4*)(ip + (long)r * LEN);        // dense 1KB seg0
    a1[r] = *(const f4*)(ip + (long)r * LEN + 256);  // dense 1KB seg1
  }

  // ================= perm phase (2 positions per thread) =================
  const int l0 = tid, l1 = tid + 256;
  const uint32_t w0 = ((const uint32_t*)mask)[0];
  bool valid0, valid1;
  if (w0 == 1u) {                              // int32 0/1
    valid0 = ((const int*)mask)[b * LEN + l0] != 0;
    valid1 = ((const int*)mask)[b * LEN + l1] != 0;
  } else if (w0 == 0x3F800000u) {              // float32 0.0/1.0
    valid0 = ((const float*)mask)[b * LEN + l0] != 0.0f;
    valid1 = ((const float*)mask)[b * LEN + l1] != 0.0f;
  } else {                                     // 1-byte bool
    valid0 = ((const unsigned char*)mask)[b * LEN + l0] != 0;
    valid1 = ((const unsigned char*)mask)[b * LEN + l1] != 0;
  }
  const bool inv0 = !valid0, inv1 = !valid1;

  uint32_t a, c, me0, me1;
  threefry2x32_k042(0u, (uint32_t)(b * LEN + l0), a, c);
  me0 = ((((a ^ c) >> 9) & 0x7FFFFFu) << 9) | (uint32_t)(511 - l0);
  threefry2x32_k042(0u, (uint32_t)(b * LEN + l1), a, c);
  me1 = ((((a ^ c) >> 9) & 0x7FFFFFu) << 9) | (uint32_t)(511 - l1);

  // order-preserving compaction: segment order = [h0w0..h0w3, h1w0..h1w3]
  const unsigned long long bal0 = __ballot(inv0);
  const unsigned long long bal1 = __ballot(inv1);
  const unsigned long long lmask = (1ull << lane) - 1ull;
  const int lower0 = __popcll(bal0 & lmask);
  const int lower1 = __popcll(bal1 & lmask);
  if (lane == 0) {
    wsum[wave] = __popcll(bal0);
    wsum[4 + wave] = __popcll(bal1);
  }
  __syncthreads();
  if (tid == 0) {
    int acc = 0;
    for (int w = 0; w < 8; ++w) { woff[w] = acc; acc += wsum[w]; }
    woff[8] = acc;
  }
  __syncthreads();
  const int n_inv = woff[8];
  const int ib0 = woff[wave] + lower0;         // # invalid with index < l0
  const int ib1 = woff[4 + wave] + lower1;     // # invalid with index < l1
  if (inv0) s_pack[ib0] = me0;
  if (inv1) s_pack[ib1] = me1;
  __syncthreads();

  // rank scans, each gated: in prefix-valid data the l0 half never scans
  int r0 = 0, r1 = 0;
  if (inv0) {
    int j = 0;
    for (; j + 8 <= n_inv; j += 8) {
      const uint4 p0 = *(const uint4*)&s_pack[j];
      const uint4 p1 = *(const uint4*)&s_pack[j + 4];
      r0 += (int)(p0.x > me0) + (int)(p0.y > me0) + (int)(p0.z > me0) +
            (int)(p0.w > me0) + (int)(p1.x > me0) + (int)(p1.y > me0) +
            (int)(p1.z > me0) + (int)(p1.w > me0);
    }
    for (; j < n_inv; ++j) r0 += (int)(s_pack[j] > me0);
  }
  if (inv1) {
    int j = 0;
    for (; j + 8 <= n_inv; j += 8) {
      const uint4 p0 = *(const uint4*)&s_pack[j];
      const uint4 p1 = *(const uint4*)&s_pack[j + 4];
      r1 += (int)(p0.x > me1) + (int)(p0.y > me1) + (int)(p0.z > me1) +
            (int)(p0.w > me1) + (int)(p1.x > me1) + (int)(p1.y > me1) +
            (int)(p1.z > me1) + (int)(p1.w > me1);
    }
    for (; j < n_inv; ++j) r1 += (int)(s_pack[j] > me1);
  }
  const int pos0 = inv0 ? r0 : n_inv + (l0 - ib0);
  const int pos1 = inv1 ? r1 : n_inv + (l1 - ib1);
  s_src[pos0] = l0;
  s_src[pos1] = l1;
  s_dst[l0] = pos0;
  s_dst[l1] = pos1;

  const int nv = LEN - n_inv;
  const int ml = nv < 1 ? 1 : nv;
  if (k == 0) {                                // one block per b writes mask_p
    mask_out[b * LEN + l0] = (l0 >= n_inv && l0 < ml) ? 1.0f : 0.0f;
    mask_out[b * LEN + l1] = (l1 >= n_inv && l1 < ml) ? 1.0f : 0.0f;
  }
  __syncthreads();                             // s_src / s_dst complete

  // ================= uu streaming phase (gather cols, scatter rows) ======
  int c0[4], c1[4];
#pragma unroll
  for (int kk = 0; kk < 4; ++kk) {
    c0[kk] = s_src[lane * 4 + kk];
    c1[kk] = s_src[256 + lane * 4 + kk];
  }
  int dr[8];
#pragma unroll
  for (int r = 0; r < 8; ++r) dr[r] = s_dst[i0 + r];

  float* myrow = &s_row[wave][0];
  float* opb = out + plane + lane * 4;

#pragma unroll
  for (int r = 0; r < 8; ++r) {
    *(f4*)(myrow + lane * 4) = a0[r];          // dense 1KB LDS write
    *(f4*)(myrow + 256 + lane * 4) = a1[r];
    f4 q0, q1;
    q0.x = myrow[c0[0]]; q0.y = myrow[c0[1]]; q0.z = myrow[c0[2]]; q0.w = myrow[c0[3]];
    q1.x = myrow[c1[0]]; q1.y = myrow[c1[1]]; q1.z = myrow[c1[2]]; q1.w = myrow[c1[3]];
    f4* op = (f4*)(opb + (long)dr[r] * LEN);
    op[0] = q0;                                // dense 1KB store (seg0)
    *(f4*)((float*)op + 256) = q1;             // dense 1KB store (seg1)
  }

  // ================= fused x/v gather + trim for this (b, k) =============
  {
    const float* xrow = xin + (long)((b << 6) + k) * LEN;
    float* orow = xout + (long)((b << 6) + k) * LEN;
    for (int p = tid; p < LEN; p += 256) {
      orow[p] = (p < ml) ? xrow[s_src[p]] : 0.0f;
    }
  }
  if (k < NCV) {
    const float* vrow = vin + (long)((b << 2) + k) * LEN;
    float* orow = vout + (long)((b << 2) + k) * LEN;
    for (int p = tid; p < LEN; p += 256) {
      orow[p] = (p < ml) ? vrow[s_src[p]] : 0.0f;
    }
  }
}

extern "C" void kernel_launch(void* const* d_in, const int* in_sizes, int n_in,
                              void* d_out, int out_size, void* d_ws, size_t ws_size,
                              hipStream_t stream) {
  const float* x  = (const float*)d_in[0];   // (64,64,512)
  const float* v  = (const float*)d_in[1];   // (64,4,512)
  const float* uu = (const float*)d_in[2];   // (64,4,512,512)
  const void*  mask = d_in[3];               // (64,1,512)

  float* out   = (float*)d_out;
  float* out_x = out;                        // 2,097,152
  float* out_v = out + 2097152;              // 131,072
  float* out_m = out + 2228224;              // 32,768
  float* out_u = out + 2260992;              // 67,108,864

  fused_trim<<<NB * NCU * LEN / 32, 256, 0, stream>>>(
      uu, out_u, x, v, out_x, out_v, out_m, mask);
}